// Round 3
// baseline (188.280 us; speedup 1.0000x reference)
//
#include <hip/hip_runtime.h>
#include <stdint.h>

#define GAMMA 0.002f
#define MDIM 4096
#define NDIM 8192
#define KDIM 512

typedef short v8s __attribute__((ext_vector_type(8)));
typedef float v4f __attribute__((ext_vector_type(4)));

__device__ __forceinline__ unsigned short f32_to_bf16_rne(float f) {
    union { float f; uint32_t u; } v; v.f = f;
    uint32_t u = v.u;
    return (unsigned short)((u + 0x7fffu + ((u >> 16) & 1u)) >> 16);
}

__device__ __forceinline__ void gl_lds16(const void* g, void* l) {
    __builtin_amdgcn_global_load_lds(
        (const __attribute__((address_space(1))) uint32_t*)g,
        (__attribute__((address_space(3))) uint32_t*)l, 16, 0, 0);
}

// One block per row: convert 512 fp32 -> bf16 (RNE) and emit -gamma*sum(x^2).
__global__ __launch_bounds__(256) void convert_rows(
    const float* __restrict__ in, unsigned short* __restrict__ outb,
    float* __restrict__ neg_g_sq) {
    int row = blockIdx.x;
    const float* src = in + (size_t)row * KDIM;
    unsigned short* dst = outb + (size_t)row * KDIM;
    int t = threadIdx.x;
    float2 f = ((const float2*)src)[t];
    ushort2 b;
    b.x = f32_to_bf16_rne(f.x);
    b.y = f32_to_bf16_rne(f.y);
    ((ushort2*)dst)[t] = b;
    float s = f.x * f.x + f.y * f.y;
    #pragma unroll
    for (int off = 32; off > 0; off >>= 1) s += __shfl_down(s, off, 64);
    __shared__ float red[4];
    if ((t & 63) == 0) red[t >> 6] = s;
    __syncthreads();
    if (t == 0) neg_g_sq[row] = -GAMMA * (red[0] + red[1] + red[2] + red[3]);
}

// 256x256 tile, BK=64, 8 waves (2M x 4N), double-buffered 128 KiB LDS,
// 4-phase-per-K-tile pipeline with counted vmcnt(6), T2 XOR-swizzle, T5 setprio.
// Epilogue: bias+exp in-register, LDS-transpose, coalesced 1-KiB row stores.
// C[m,n] = exp(arow[m] + ccol[n] + 2*gamma*dot(x[m], sv[n]))
#define QUAD(MH, NH)                                                          \
  do {                                                                        \
    __builtin_amdgcn_s_setprio(1);                                            \
    _Pragma("unroll")                                                         \
    for (int kk = 0; kk < 2; ++kk) {                                          \
      _Pragma("unroll")                                                       \
      for (int i2 = 0; i2 < 4; ++i2) {                                        \
        _Pragma("unroll")                                                     \
        for (int j2 = 0; j2 < 2; ++j2) {                                      \
          acc[(MH)*4 + i2][(NH)*2 + j2] =                                     \
              __builtin_amdgcn_mfma_f32_16x16x32_bf16(                        \
                  bf[(NH)*2 + j2][kk], af[i2][kk],                            \
                  acc[(MH)*4 + i2][(NH)*2 + j2], 0, 0, 0);                    \
        }                                                                     \
      }                                                                       \
    }                                                                         \
    __builtin_amdgcn_s_setprio(0);                                            \
  } while (0)

__global__ __launch_bounds__(512, 2) void rbf_gemm(
    const unsigned short* __restrict__ A,   // [4096,512] bf16
    const unsigned short* __restrict__ B,   // [8192,512] bf16
    const float* __restrict__ arow,         // [4096]  = -g*||x||^2
    const float* __restrict__ ccol,         // [8192]  = -g*||sv||^2
    float* __restrict__ out) {

    // LDS layout per buffer (64 KiB, 2 buffers):
    //  +0      A-half0 (rows 0-127   of A tile, [128][64] bf16, swizzled)
    //  +16384  A-half1 (rows 128-255)
    //  +32768  B-half0 (rows 0-127 of B tile)
    //  +49152  B-half1
    __shared__ __align__(16) char smem[131072];

    const int tid  = threadIdx.x;
    const int lane = tid & 63;
    const int wave = tid >> 6;          // 0..7
    const int wm   = wave >> 2;         // 0..1 : 128-row slice
    const int wn   = wave & 3;          // 0..3 : 64-col slice

    // bijective XCD swizzle (512 = 8*64)
    const int bid  = blockIdx.x;
    const int swz  = ((bid & 7) << 6) | (bid >> 3);
    const int row0 = (swz >> 5) << 8;   // 0..3840
    const int col0 = (swz & 31) << 8;   // 0..7936

    // ---- staging (global -> linear LDS, source pre-inverse-swizzled) ----
    // thread covers rows (tid>>3) and 64+(tid>>3) of a 128-row half, 16B at
    // col chunk (tid&7); swizzle col ^= ((row&7)<<4).
    const int rA   = tid >> 3;
    const int colS = ((tid & 7) << 4) ^ ((rA & 7) << 4);
    const char* aSrc = (const char*)A + ((size_t)(row0 + rA) << 10) + colS;
    const char* bSrc = (const char*)B + ((size_t)(col0 + rA) << 10) + colS;

    auto stageA = [&](int tt, int h) {
        const char* s = aSrc + tt * 128 + h * 131072;            // k-off + 128 rows
        char* d = smem + ((tt & 1) << 16) + h * 16384 + tid * 16;
        gl_lds16(s, d);
        gl_lds16(s + 65536, d + 8192);                           // +64 rows
    };
    auto stageB = [&](int tt, int h) {
        const char* s = bSrc + tt * 128 + h * 131072;
        char* d = smem + ((tt & 1) << 16) + 32768 + h * 16384 + tid * 16;
        gl_lds16(s, d);
        gl_lds16(s + 65536, d + 8192);
    };

    // ---- fragment read addresses (swizzled) ----
    const int l15   = lane & 15;
    const int colK0 = ((lane >> 4) ^ (lane & 7)) << 4;       // kk=0 col bytes
    const int aBase0 = wm * 16384 + l15 * 128 + colK0;
    const int aBase1 = aBase0 ^ 64;                          // kk=1
    const int bBase0 = 32768 + (wn >> 1) * 16384 + (wn & 1) * 8192
                       + l15 * 128 + colK0;
    const int bBase1 = bBase0 ^ 64;

    v4f acc[8][4];
    #pragma unroll
    for (int i = 0; i < 8; ++i)
        #pragma unroll
        for (int j = 0; j < 4; ++j) acc[i][j] = (v4f)0.0f;

    v8s af[4][2];   // current m-half fragments
    v8s bf[4][2];   // all 4 n-fragments of current tile

    // prologue: issue 7 half-tiles: B0(0) B1(0) A0(0) A1(0) B0(1) B1(1) A0(1)
    stageB(0, 0); stageB(0, 1); stageA(0, 0); stageA(0, 1);
    stageB(1, 0); stageB(1, 1); stageA(1, 0);
    asm volatile("s_waitcnt vmcnt(6)" ::: "memory");   // tile 0 fully landed
    __builtin_amdgcn_s_barrier();

    #pragma unroll
    for (int t = 0; t < 8; ++t) {
        const int bufo = (t & 1) << 16;
        // ---- phase 0: ds_read A-mh0 + all B; stage A1(t+1); quad(0,0) ----
        #pragma unroll
        for (int i2 = 0; i2 < 4; ++i2) {
            af[i2][0] = *(const v8s*)(smem + bufo + aBase0 + i2 * 2048);
            af[i2][1] = *(const v8s*)(smem + bufo + aBase1 + i2 * 2048);
        }
        #pragma unroll
        for (int j = 0; j < 4; ++j) {
            bf[j][0] = *(const v8s*)(smem + bufo + bBase0 + j * 2048);
            bf[j][1] = *(const v8s*)(smem + bufo + bBase1 + j * 2048);
        }
        if (t + 1 < 8) stageA(t + 1, 1);
        __builtin_amdgcn_s_barrier();
        __builtin_amdgcn_sched_barrier(0);
        QUAD(0, 0);
        __builtin_amdgcn_s_barrier();
        // ---- phase 1: stage B0(t+2); quad(0,1) ----
        if (t + 2 < 8) stageB(t + 2, 0);
        __builtin_amdgcn_s_barrier();
        __builtin_amdgcn_sched_barrier(0);
        QUAD(0, 1);
        __builtin_amdgcn_s_barrier();
        // ---- phase 2: ds_read A-mh1; stage B1(t+2); quad(1,0) ----
        #pragma unroll
        for (int i2 = 0; i2 < 4; ++i2) {
            af[i2][0] = *(const v8s*)(smem + bufo + aBase0 + 8192 + i2 * 2048);
            af[i2][1] = *(const v8s*)(smem + bufo + aBase1 + 8192 + i2 * 2048);
        }
        if (t + 2 < 8) stageB(t + 2, 1);
        __builtin_amdgcn_s_barrier();
        __builtin_amdgcn_sched_barrier(0);
        QUAD(1, 0);
        __builtin_amdgcn_s_barrier();
        // ---- phase 3: stage A0(t+2); quad(1,1); counted vmcnt ----
        if (t + 2 < 8) stageA(t + 2, 0);
        __builtin_amdgcn_s_barrier();
        __builtin_amdgcn_sched_barrier(0);
        QUAD(1, 1);
        if (t < 6)       asm volatile("s_waitcnt vmcnt(6)" ::: "memory");
        else if (t == 6) asm volatile("s_waitcnt vmcnt(0)" ::: "memory");
        __builtin_amdgcn_s_barrier();
    }

    // ---- epilogue v2: bias+exp in-register, LDS transpose, coalesced stores
    float* sb = (float*)smem;              // [0..255]=arow slice, [256..511]=ccol
    if (tid < 256) sb[tid] = arow[row0 + tid];
    else           sb[tid] = ccol[col0 + tid - 256];
    __syncthreads();

    const float tg = 2.0f * GAMMA;
    const int qq = lane >> 4;              // 0..3 : 4-col granule within 16
    #pragma unroll
    for (int i = 0; i < 8; ++i) {
        const int r_l = wm * 128 + i * 16 + l15;
        const float ra = sb[r_l];
        #pragma unroll
        for (int j = 0; j < 4; ++j) {
            #pragma unroll
            for (int v = 0; v < 4; ++v) {
                const int c_l = wn * 64 + j * 16 + (qq << 2) + v;
                acc[i][j][v] = __expf(fmaf(tg, acc[i][j][v], ra + sb[256 + c_l]));
            }
        }
    }

    // 4 chunks of 64 rows; chunk buffer [64][256] f32 = 64 KiB at smem+4096
    // (doesn't overlap the bias arrays at smem[0..2047]).
    float* tb = (float*)(smem + 4096);
    #pragma unroll
    for (int ch = 0; ch < 4; ++ch) {
        // writers: the wm group owning rows ch*64..ch*64+63
        if (wm == (ch >> 1)) {
            #pragma unroll
            for (int ii = 0; ii < 4; ++ii) {
                const int i  = (ch & 1) * 4 + ii;    // compile-time acc index
                const int rl = ii * 16 + l15;        // row within chunk
                #pragma unroll
                for (int j = 0; j < 4; ++j) {
                    const int g = wn * 16 + j * 4 + qq;   // 16-B granule 0..63
                    *(v4f*)&tb[rl * 256 + ((g ^ (rl & 7)) << 2)] = acc[i][j];
                }
            }
        }
        __syncthreads();
        // readers/storers: all 8 waves, 8 full rows each, 1-KiB segments
        #pragma unroll
        for (int rr = 0; rr < 8; ++rr) {
            const int rl = wave * 8 + rr;
            v4f val = *(const v4f*)&tb[rl * 256 + ((lane ^ (rl & 7)) << 2)];
            *(v4f*)(out + (size_t)(row0 + ch * 64 + rl) * NDIM + col0 + lane * 4) = val;
        }
        __syncthreads();
    }
}

extern "C" void kernel_launch(void* const* d_in, const int* in_sizes, int n_in,
                              void* d_out, int out_size, void* d_ws, size_t ws_size,
                              hipStream_t stream) {
    const float* x  = (const float*)d_in[0];   // [4096,512]
    const float* sv = (const float*)d_in[1];   // [8192,512]
    float* out = (float*)d_out;

    // ws layout: xb (4 MiB) | svb (8 MiB) | arow (16 KiB) | ccol (32 KiB)
    unsigned short* xb  = (unsigned short*)d_ws;
    unsigned short* svb = xb + (size_t)MDIM * KDIM;
    float* arow = (float*)(svb + (size_t)NDIM * KDIM);
    float* ccol = arow + MDIM;

    hipLaunchKernelGGL(convert_rows, dim3(MDIM), dim3(256), 0, stream, x, xb, arow);
    hipLaunchKernelGGL(convert_rows, dim3(NDIM), dim3(256), 0, stream, sv, svb, ccol);
    hipLaunchKernelGGL(rbf_gemm, dim3((MDIM / 256) * (NDIM / 256)), dim3(512), 0,
                       stream, xb, svb, arow, ccol, out);
}

// Round 4
// 186.977 us; speedup vs baseline: 1.0070x; 1.0070x over previous
//
#include <hip/hip_runtime.h>
#include <stdint.h>

#define GAMMA 0.002f
#define MDIM 4096
#define NDIM 8192
#define KDIM 512

typedef short v8s __attribute__((ext_vector_type(8)));
typedef float v4f __attribute__((ext_vector_type(4)));

__device__ __forceinline__ unsigned short f32_to_bf16_rne(float f) {
    union { float f; uint32_t u; } v; v.f = f;
    uint32_t u = v.u;
    return (unsigned short)((u + 0x7fffu + ((u >> 16) & 1u)) >> 16);
}

__device__ __forceinline__ void gl_lds16(const void* g, void* l) {
    __builtin_amdgcn_global_load_lds(
        (const __attribute__((address_space(1))) uint32_t*)g,
        (__attribute__((address_space(3))) uint32_t*)l, 16, 0, 0);
}

// One block per row: convert 512 fp32 -> bf16 (RNE) and emit -gamma*sum(x^2).
__global__ __launch_bounds__(256) void convert_rows(
    const float* __restrict__ in, unsigned short* __restrict__ outb,
    float* __restrict__ neg_g_sq) {
    int row = blockIdx.x;
    const float* src = in + (size_t)row * KDIM;
    unsigned short* dst = outb + (size_t)row * KDIM;
    int t = threadIdx.x;
    float2 f = ((const float2*)src)[t];
    ushort2 b;
    b.x = f32_to_bf16_rne(f.x);
    b.y = f32_to_bf16_rne(f.y);
    ((ushort2*)dst)[t] = b;
    float s = f.x * f.x + f.y * f.y;
    #pragma unroll
    for (int off = 32; off > 0; off >>= 1) s += __shfl_down(s, off, 64);
    __shared__ float red[4];
    if ((t & 63) == 0) red[t >> 6] = s;
    __syncthreads();
    if (t == 0) neg_g_sq[row] = -GAMMA * (red[0] + red[1] + red[2] + red[3]);
}

// v4: 128x128 tile, 4 waves (2x2), BK=32, TRIPLE-buffered LDS (48 KiB) for
// 3 blocks/CU occupancy; counted vmcnt(4) depth-2 prefetch; XOR-swizzled LDS;
// coalesced LDS-transpose epilogue.
// C[m,n] = exp(arow[m] + ccol[n] + 2*gamma*dot(x[m], sv[n]))
__global__ __launch_bounds__(256, 3) void rbf_gemm(
    const unsigned short* __restrict__ A,   // [4096,512] bf16
    const unsigned short* __restrict__ B,   // [8192,512] bf16
    const float* __restrict__ arow,         // [4096]  = -g*||x||^2
    const float* __restrict__ ccol,         // [8192]  = -g*||sv||^2
    float* __restrict__ out) {

    // LDS: 3 buffers x (A 8 KiB + B 8 KiB) = 48 KiB at 0..49151
    //      sb_r (128 f32) at 49152, sb_c (128 f32) at 49664.  total 50176 B.
    // Epilogue tb [64][128] f32 = 32 KiB reuses 0..32767.
    __shared__ __align__(16) char smem[50176];

    const int tid  = threadIdx.x;
    const int lane = tid & 63;
    const int wave = tid >> 6;          // 0..3
    const int wm   = wave >> 1;         // 0..1 : 64-row slice
    const int wn   = wave & 1;          // 0..1 : 64-col slice

    // bijective XCD swizzle (2048 = 8*256)
    const int bid  = blockIdx.x;
    const int swz  = ((bid & 7) << 8) | (bid >> 3);
    const int row0 = (swz & 31) << 7;   // m tile
    const int col0 = (swz >> 5) << 7;   // n tile

    // ---- staging: tile = [128 rows][32 k] bf16 (64 B/row), rows r=tid>>2 and
    // r+64, 16-B chunk c=tid&3; swizzle byte_col ^= ((r&3)<<4) applied on the
    // GLOBAL source (LDS dest stays linear: tid*16 / +4096).
    const int rS  = tid >> 2;                         // 0..63
    const int cSw = ((tid & 3) << 4) ^ ((rS & 3) << 4);
    const char* aS = (const char*)A + ((size_t)(row0 + rS) << 10) + cSw;
    const char* bS = (const char*)B + ((size_t)(col0 + rS) << 10) + cSw;
    char* dA = smem + tid * 16;
    char* dB = smem + 8192 + tid * 16;

    #define STAGE(t)                                                          \
      do {                                                                    \
        const int _b = ((t) % 3) * 16384;                                     \
        const char* _sa = aS + (t) * 64;                                      \
        const char* _sb = bS + (t) * 64;                                      \
        gl_lds16(_sa,          dA + _b);                                      \
        gl_lds16(_sa + 65536,  dA + _b + 4096);                               \
        gl_lds16(_sb,          dB + _b);                                      \
        gl_lds16(_sb + 65536,  dB + _b + 4096);                               \
      } while (0)

    // ---- fragment addresses (swizzled reads) ----
    const int q   = lane >> 4;          // 0..3 : k-chunk q*8
    const int l15 = lane & 15;
    const int ra0 = wm * 64 + l15;
    const int aOff = ra0 * 64 + (((q << 4)) ^ ((ra0 & 3) << 4));
    const int rb0 = wn * 64 + l15;
    const int bOff = 8192 + rb0 * 64 + (((q << 4)) ^ ((rb0 & 3) << 4));

    v4f acc[4][4];
    #pragma unroll
    for (int i = 0; i < 4; ++i)
        #pragma unroll
        for (int j = 0; j < 4; ++j) acc[i][j] = (v4f)0.0f;

    // prologue: 2 tiles in flight; bias loads; wait tile0 (vmcnt: 8 out, keep 4)
    STAGE(0); STAGE(1);
    if (tid < 128) ((float*)(smem + 49152))[tid] = arow[row0 + tid];
    else           ((float*)(smem + 49664))[tid - 128] = ccol[col0 + tid - 128];
    asm volatile("s_waitcnt vmcnt(4)" ::: "memory");
    __builtin_amdgcn_s_barrier();

    #pragma unroll
    for (int t = 0; t < 16; ++t) {
        if (t + 2 < 16) STAGE(t + 2);
        const int bo = (t % 3) * 16384;
        v8s af[4], bf[4];
        #pragma unroll
        for (int i = 0; i < 4; ++i) af[i] = *(const v8s*)(smem + bo + aOff + i * 1024);
        #pragma unroll
        for (int j = 0; j < 4; ++j) bf[j] = *(const v8s*)(smem + bo + bOff + j * 1024);
        __builtin_amdgcn_s_setprio(1);
        #pragma unroll
        for (int i = 0; i < 4; ++i)
            #pragma unroll
            for (int j = 0; j < 4; ++j)
                acc[i][j] = __builtin_amdgcn_mfma_f32_16x16x32_bf16(
                    bf[j], af[i], acc[i][j], 0, 0, 0);
        __builtin_amdgcn_s_setprio(0);
        if (t < 14)      asm volatile("s_waitcnt vmcnt(4)" ::: "memory");
        else if (t == 14) asm volatile("s_waitcnt vmcnt(0)" ::: "memory");
        __builtin_amdgcn_s_barrier();
    }
    #undef STAGE

    // ---- epilogue: bias+exp in-register, LDS transpose, 512-B row segments
    const float tg = 2.0f * GAMMA;
    const float* sbr = (const float*)(smem + 49152);
    const float* sbc = (const float*)(smem + 49664);
    #pragma unroll
    for (int i = 0; i < 4; ++i) {
        const float ra = sbr[wm * 64 + i * 16 + l15];
        #pragma unroll
        for (int j = 0; j < 4; ++j) {
            #pragma unroll
            for (int v = 0; v < 4; ++v) {
                const int c_l = wn * 64 + j * 16 + (q << 2) + v;
                acc[i][j][v] = __expf(fmaf(tg, acc[i][j][v], ra + sbc[c_l]));
            }
        }
    }

    float* tb = (float*)smem;            // [64][128] f32, granule-XOR swizzled
    #pragma unroll
    for (int ch = 0; ch < 2; ++ch) {
        if (wm == ch) {
            #pragma unroll
            for (int i = 0; i < 4; ++i) {
                const int rl = i * 16 + l15;           // row within chunk
                #pragma unroll
                for (int j = 0; j < 4; ++j) {
                    const int g = wn * 16 + j * 4 + q; // 16-B granule 0..31
                    *(v4f*)&tb[rl * 128 + ((g ^ (rl & 31)) << 2)] = acc[i][j];
                }
            }
        }
        __syncthreads();
        #pragma unroll
        for (int rr = 0; rr < 8; ++rr) {
            const int rl = wave * 16 + (rr << 1) + (lane >> 5);
            v4f val = *(const v4f*)&tb[rl * 128 + (((lane & 31) ^ (rl & 31)) << 2)];
            *(v4f*)(out + (size_t)(row0 + ch * 64 + rl) * NDIM + col0 +
                    ((lane & 31) << 2)) = val;
        }
        __syncthreads();
    }
}

extern "C" void kernel_launch(void* const* d_in, const int* in_sizes, int n_in,
                              void* d_out, int out_size, void* d_ws, size_t ws_size,
                              hipStream_t stream) {
    const float* x  = (const float*)d_in[0];   // [4096,512]
    const float* sv = (const float*)d_in[1];   // [8192,512]
    float* out = (float*)d_out;

    // ws layout: xb (4 MiB) | svb (8 MiB) | arow (16 KiB) | ccol (32 KiB)
    unsigned short* xb  = (unsigned short*)d_ws;
    unsigned short* svb = xb + (size_t)MDIM * KDIM;
    float* arow = (float*)(svb + (size_t)NDIM * KDIM);
    float* ccol = arow + MDIM;

    hipLaunchKernelGGL(convert_rows, dim3(MDIM), dim3(256), 0, stream, x, xb, arow);
    hipLaunchKernelGGL(convert_rows, dim3(NDIM), dim3(256), 0, stream, sv, svb, ccol);
    hipLaunchKernelGGL(rbf_gemm, dim3((MDIM / 128) * (NDIM / 128)), dim3(256), 0,
                       stream, xb, svb, arow, ccol, out);
}